// Round 6
// baseline (143.439 us; speedup 1.0000x reference)
//
#include <hip/hip_runtime.h>

#define DIMS 1024
#define KNN_K 8
#define BMT 64          // x rows per block (LDS-resident A tile)
#define BCOLS 512       // y cols per block (4 waves x 128)
#define KHALF 512       // K half resident in LDS (64 rows x 512 k x 2B = 64KB)

typedef __bf16 bf16;
typedef __bf16 bf16x8 __attribute__((ext_vector_type(8)));
typedef __bf16 bf16x4 __attribute__((ext_vector_type(4)));
typedef float f32x4 __attribute__((ext_vector_type(4)));

// branchless insert into ascending sorted-8 list (drops the largest)
__device__ __forceinline__ void ins8(float (&lst)[8], float d) {
  float c = d;
  #pragma unroll
  for (int i = 0; i < 8; ++i) {
    float lo = fminf(lst[i], c);
    c = fmaxf(lst[i], c);
    lst[i] = lo;
  }
}

__device__ __forceinline__ void gload_lds16(const void* g, void* l) {
  __builtin_amdgcn_global_load_lds(
      (const __attribute__((address_space(1))) void*)g,
      (__attribute__((address_space(3))) void*)l, 16, 0, 0);
}

// ---- prep: norms (+ optional bf16 convert) fused with min_dists->out copy --
template<bool PRE>
__global__ void prep_kernel(const float* __restrict__ x, const float* __restrict__ y,
                            float* __restrict__ x2, float* __restrict__ y2,
                            bf16* __restrict__ xb, bf16* __restrict__ yb,
                            const float4* __restrict__ mind4, float4* __restrict__ out4,
                            int n4, int B, int M, int nNormBlocks) {
  if ((int)blockIdx.x >= nNormBlocks) {        // tail blocks: full-buffer copy
    int i = ((int)blockIdx.x - nNormBlocks) * 256 + threadIdx.x;
    if (i < n4) out4[i] = mind4[i];
    return;
  }
  int wv = threadIdx.x >> 6;
  int lane = threadIdx.x & 63;
  int row = blockIdx.x * 4 + wv;
  const float* src;
  float* dst;
  bf16* bdst;
  if (row < M) {
    src = y + (size_t)row * DIMS; dst = y2 + row; bdst = yb + (size_t)row * DIMS;
  } else {
    int r = row - M;
    if (r >= B) return;
    src = x + (size_t)r * DIMS; dst = x2 + r; bdst = xb + (size_t)r * DIMS;
  }
  float s = 0.f;
  #pragma unroll
  for (int q = 0; q < DIMS / 4; q += 64) {
    float4 v = ((const float4*)src)[q + lane];
    s = fmaf(v.x, v.x, s); s = fmaf(v.y, v.y, s);
    s = fmaf(v.z, v.z, s); s = fmaf(v.w, v.w, s);
    if (PRE) {
      bf16x4 bv = {(bf16)v.x, (bf16)v.y, (bf16)v.z, (bf16)v.w};
      *(bf16x4*)(bdst + (size_t)(q + lane) * 4) = bv;
    }
  }
  #pragma unroll
  for (int off = 32; off; off >>= 1) s += __shfl_xor(s, off);
  if (lane == 0) *dst = s;
}

// ---------------- phase A: x-tile in LDS, y streamed; reg-pipelined K loop --
// grid: 512 blocks (rowblk = bid>>4, colchunk = bid&15 -> colchunk%8 per XCD).
// block: 256 threads = 4 waves; wave wv owns cols c0+wv*128..+127, rows r0..+63.
template<bool PRE>
__global__ __launch_bounds__(256, 2) void knn_stream(
    const float* __restrict__ xf, const float* __restrict__ yf,
    const bf16* __restrict__ xb, const bf16* __restrict__ yb,
    const float* __restrict__ x2, const float* __restrict__ y2,
    float* __restrict__ topk_out,           // [B][nch*8] squared dists
    const int* __restrict__ xsp, const int* __restrict__ ysp,
    int B, int M, int nch) {
  __shared__ __align__(16) char smem[65536]; // A tile [64 rows][64 swz 16B slots]
  __shared__ float x2s[BMT];
  __shared__ float y2s[BCOLS];
  float* eps = (float*)smem;                 // epilogue reuse: col-major [128][66]
  float* part = (float*)(smem + 36864);      // [256][8]

  const int tid = threadIdx.x;
  const int wv = tid >> 6, l = tid & 63;
  const int g4 = l >> 4, l16 = l & 15;
  const int bid = blockIdx.x;
  const int colchunk = bid & 15, rowblk = bid >> 4;
  const int r0 = rowblk * BMT, c0 = colchunk * BCOLS;
  const int xs = *xsp, ys = *ysp;
  const float FINF = __builtin_inff();

  if (tid < BMT) x2s[tid] = x2[r0 + tid];
  y2s[tid] = y2[c0 + tid];
  y2s[256 + tid] = y2[c0 + 256 + tid];

  // per-lane base pointers for the y fragment stream
  const bf16*  ybl = yb + (size_t)(c0 + wv * 128 + l16) * DIMS + g4 * 8;
  const float* yfl = yf + (size_t)(c0 + wv * 128 + l16) * DIMS + g4 * 8;

  auto STAGE = [&](int kh) {                 // 64KB x-tile: rows p*4+wv, slot l
    #pragma unroll
    for (int p = 0; p < 16; ++p) {
      int row = p * 4 + wv;
      int cs = l ^ (row & 7);                // inverse-swizzled global chunk
      if (PRE) {
        gload_lds16(xb + (size_t)(r0 + row) * DIMS + kh * KHALF + cs * 8,
                    smem + p * 4096 + tid * 16);
      } else {
        const float* g = xf + (size_t)(r0 + row) * DIMS + kh * KHALF + cs * 8;
        float4 a0 = *(const float4*)g;
        float4 a1 = *(const float4*)(g + 4);
        bf16x8 bx = {(bf16)a0.x, (bf16)a0.y, (bf16)a0.z, (bf16)a0.w,
                     (bf16)a1.x, (bf16)a1.y, (bf16)a1.z, (bf16)a1.w};
        *(bf16x8*)(smem + p * 4096 + tid * 16) = bx;
      }
    }
  };

  auto LA = [&](bf16x8 (&af)[4], int kt) {   // A frags from LDS (swizzled)
    #pragma unroll
    for (int mi = 0; mi < 4; ++mi) {
      int row = mi * 16 + l16;
      int slot = (kt * 4 + g4) ^ (row & 7);
      af[mi] = *(const bf16x8*)(smem + row * 1024 + slot * 16);
    }
  };

  auto LB = [&](bf16x8 (&bv)[8], int koff) { // B frags streamed from global
    #pragma unroll
    for (int ct = 0; ct < 8; ++ct) {
      if (PRE) {
        bv[ct] = *(const bf16x8*)(ybl + (size_t)ct * 16 * DIMS + koff);
      } else {
        const float* g = yfl + (size_t)ct * 16 * DIMS + koff;
        float4 b0 = *(const float4*)g;
        float4 b1 = *(const float4*)(g + 4);
        bv[ct] = (bf16x8){(bf16)b0.x, (bf16)b0.y, (bf16)b0.z, (bf16)b0.w,
                          (bf16)b1.x, (bf16)b1.y, (bf16)b1.z, (bf16)b1.w};
      }
    }
  };

  f32x4 acc[8][4];
  #pragma unroll
  for (int ct = 0; ct < 8; ++ct)
    #pragma unroll
    for (int mi = 0; mi < 4; ++mi)
      acc[ct][mi] = (f32x4){0.f, 0.f, 0.f, 0.f};

  auto FMA = [&](bf16x8 (&af)[4], bf16x8 (&bv)[8]) {
    __builtin_amdgcn_s_setprio(1);
    #pragma unroll
    for (int ct = 0; ct < 8; ++ct)
      #pragma unroll
      for (int mi = 0; mi < 4; ++mi)
        acc[ct][mi] = __builtin_amdgcn_mfma_f32_16x16x32_bf16(af[mi], bv[ct], acc[ct][mi], 0, 0, 0);
    __builtin_amdgcn_s_setprio(0);
  };

  bf16x8 a0[4], a1[4], b0[8], b1[8];

  // ---- prologue: stage half 0; y-prefetch rides behind the stage ----
  STAGE(0);
  if (PRE) {
    LB(b0, 0); LB(b1, 32);
    asm volatile("s_waitcnt vmcnt(16)" ::: "memory"); // stage landed; b0/b1 fly
    __builtin_amdgcn_s_barrier();
    __builtin_amdgcn_sched_barrier(0);
  } else {
    __syncthreads();
    LB(b0, 0); LB(b1, 32);
  }
  LA(a0, 0); LA(a1, 1);

  // ---- kh = 0: 16 k-tiles, 2-deep register pipeline ----
  #pragma unroll
  for (int kt2 = 0; kt2 < 8; ++kt2) {
    FMA(a0, b0);
    if (kt2 < 7) { LB(b0, (kt2 * 2 + 2) * 32); LA(a0, kt2 * 2 + 2); }
    FMA(a1, b1);
    if (kt2 < 7) { LB(b1, (kt2 * 2 + 3) * 32); LA(a1, kt2 * 2 + 3); }
  }

  // ---- half transition: restage LDS, keep y-prefetch in flight ----
  if (PRE) {
    __builtin_amdgcn_s_barrier();            // all waves done reading half-0 LDS
    STAGE(1);
    LB(b0, KHALF); LB(b1, KHALF + 32);
    asm volatile("s_waitcnt vmcnt(16)" ::: "memory");
    __builtin_amdgcn_s_barrier();
    __builtin_amdgcn_sched_barrier(0);
  } else {
    __syncthreads();
    STAGE(1);
    __syncthreads();
    LB(b0, KHALF); LB(b1, KHALF + 32);
  }
  LA(a0, 0); LA(a1, 1);

  // ---- kh = 1 ----
  #pragma unroll
  for (int kt2 = 0; kt2 < 8; ++kt2) {
    FMA(a0, b0);
    if (kt2 < 7) { LB(b0, KHALF + (kt2 * 2 + 2) * 32); LA(a0, kt2 * 2 + 2); }
    FMA(a1, b1);
    if (kt2 < 7) { LB(b1, KHALF + (kt2 * 2 + 3) * 32); LA(a1, kt2 * 2 + 3); }
  }

  // ---- epilogue: 4 wave phases through col-major eps [128 cols][66] ----
  float t8[8];
  #pragma unroll
  for (int k = 0; k < 8; ++k) t8[k] = FINF;

  #pragma unroll
  for (int w = 0; w < 4; ++w) {
    __syncthreads();                         // eps free (compute / prev scan done)
    if (wv == w) {
      #pragma unroll
      for (int ct = 0; ct < 8; ++ct)
        #pragma unroll
        for (int mi = 0; mi < 4; ++mi)
          #pragma unroll
          for (int j = 0; j < 4; ++j) {
            int rl = mi * 16 + g4 * 4 + j;   // x row within block
            int cl = ct * 16 + l16;          // y col within wave strip
            float sq = fmaxf(x2s[rl] + y2s[w * 128 + cl] - 2.f * acc[ct][mi][j], 0.f);
            if (xs + r0 + rl == ys + c0 + w * 128 + cl) sq = FINF;
            eps[cl * 66 + rl] = sq;
          }
    }
    __syncthreads();
    {
      int row = tid & 63, q = tid >> 6;      // 4 threads/row, 32 cols each
      #pragma unroll 4
      for (int i = 0; i < 32; ++i) {
        float d = eps[(q * 32 + i) * 66 + row];
        if (d < t8[7]) ins8(t8, d);
      }
    }
  }
  #pragma unroll
  for (int k = 0; k < 8; ++k) part[tid * 8 + k] = t8[k];
  __syncthreads();
  if (tid < 64) {                            // merge 4 quarter-scans per row
    float f8[8];
    #pragma unroll
    for (int k = 0; k < 8; ++k) f8[k] = FINF;
    #pragma unroll
    for (int q = 0; q < 4; ++q)
      #pragma unroll
      for (int v = 0; v < 8; ++v) {
        float d = part[(q * 64 + tid) * 8 + v];
        if (d < f8[7]) ins8(f8, d);
      }
    float* o = topk_out + (size_t)(r0 + tid) * (nch * 8) + colchunk * 8;
    #pragma unroll
    for (int k = 0; k < 8; ++k) o[k] = f8[k];
  }
}

// ---------------- phase B: merge chunk candidates + running min_dists ------
__global__ void knn_phaseB(const float* __restrict__ topk,
                           const float* __restrict__ mind_in,
                           float* __restrict__ out,
                           const int* __restrict__ xsp, int B, int nch) {
  int r = blockIdx.x * blockDim.x + threadIdx.x;
  if (r >= B) return;
  int x_start = *xsp;
  const float FINF = __builtin_inff();
  float lst[8];
  #pragma unroll
  for (int k = 0; k < 8; ++k) lst[k] = FINF;
  const int nc = nch * 8;
  const float* rowp = topk + (size_t)r * nc;
  for (int v = 0; v < nc; ++v) {
    float d = sqrtf(rowp[v]);
    if (d < lst[7]) ins8(lst, d);
  }
  const float* cur = mind_in + (size_t)(x_start + r) * KNN_K;
  #pragma unroll
  for (int k = 0; k < 8; ++k) {
    float d = cur[k];
    if (d < lst[7]) ins8(lst, d);
  }
  #pragma unroll
  for (int k = 0; k < 8; ++k) out[(size_t)(x_start + r) * KNN_K + k] = lst[k];
}

extern "C" void kernel_launch(void* const* d_in, const int* in_sizes, int n_in,
                              void* d_out, int out_size, void* d_ws, size_t ws_size,
                              hipStream_t stream) {
  const float* x = (const float*)d_in[0];
  const float* y = (const float*)d_in[1];
  const float* mind = (const float*)d_in[2];
  const int* xsp = (const int*)d_in[3];
  const int* ysp = (const int*)d_in[4];
  float* out = (float*)d_out;

  const int B = in_sizes[0] / DIMS;       // 2048
  const int M = in_sizes[1] / DIMS;       // 8192
  const int nch = M / BCOLS;              // 16

  float* y2 = (float*)d_ws;               // [M]
  float* x2 = y2 + M;                     // [B]
  float* topk = x2 + B;                   // [B][nch*8]
  size_t base = ((size_t)(M + B) + (size_t)B * nch * 8) * 4;
  base = (base + 255) & ~(size_t)255;
  bf16* xbw = (bf16*)((char*)d_ws + base);
  bf16* ybw = xbw + (size_t)B * DIMS;
  size_t need = base + ((size_t)B + (size_t)M) * DIMS * 2;
  bool pre = ws_size >= need;

  int nNorm = (B + M + 3) / 4;
  int n4 = out_size / 4;
  int nCopy = (n4 + 255) / 256;
  if (pre)
    prep_kernel<true><<<nNorm + nCopy, 256, 0, stream>>>(
        x, y, x2, y2, xbw, ybw, (const float4*)mind, (float4*)out, n4, B, M, nNorm);
  else
    prep_kernel<false><<<nNorm + nCopy, 256, 0, stream>>>(
        x, y, x2, y2, xbw, ybw, (const float4*)mind, (float4*)out, n4, B, M, nNorm);

  int nBlocks = (B / BMT) * nch;          // 32 x 16 = 512
  if (pre)
    knn_stream<true><<<nBlocks, 256, 0, stream>>>(x, y, xbw, ybw, x2, y2, topk, xsp, ysp, B, M, nch);
  else
    knn_stream<false><<<nBlocks, 256, 0, stream>>>(x, y, xbw, ybw, x2, y2, topk, xsp, ysp, B, M, nch);

  knn_phaseB<<<(B + 255) / 256, 256, 0, stream>>>(topk, mind, out, xsp, B, nch);
}

// Round 7
// 131.775 us; speedup vs baseline: 1.0885x; 1.0885x over previous
//
#include <hip/hip_runtime.h>

#define DIMS 1024
#define KNN_K 8
#define BM 256
#define BN 256
#define KT 64
#define NT (DIMS / KT)   // 16 K-tiles

typedef __bf16 bf16;
typedef __bf16 bf16x8 __attribute__((ext_vector_type(8)));
typedef __bf16 bf16x4 __attribute__((ext_vector_type(4)));
typedef float f32x4 __attribute__((ext_vector_type(4)));

#define BAR() asm volatile("s_barrier" ::: "memory")

// branchless insert into ascending sorted-8 list (drops the largest)
__device__ __forceinline__ void ins8(float (&lst)[8], float d) {
  float c = d;
  #pragma unroll
  for (int i = 0; i < 8; ++i) {
    float lo = fminf(lst[i], c);
    c = fmaxf(lst[i], c);
    lst[i] = lo;
  }
}

__device__ __forceinline__ void gload_lds16(const void* g, void* l) {
  __builtin_amdgcn_global_load_lds(
      (const __attribute__((address_space(1))) void*)g,
      (__attribute__((address_space(3))) void*)l, 16, 0, 0);
}

// ---- prep: norms (+ optional bf16 convert) fused with min_dists->out copy --
template<bool PRE>
__global__ void prep_kernel(const float* __restrict__ x, const float* __restrict__ y,
                            float* __restrict__ x2, float* __restrict__ y2,
                            bf16* __restrict__ xb, bf16* __restrict__ yb,
                            const float4* __restrict__ mind4, float4* __restrict__ out4,
                            int n4, int B, int M, int nNormBlocks) {
  if ((int)blockIdx.x >= nNormBlocks) {        // tail blocks: full-buffer copy
    int i = ((int)blockIdx.x - nNormBlocks) * 256 + threadIdx.x;
    if (i < n4) out4[i] = mind4[i];
    return;
  }
  int wv = threadIdx.x >> 6;
  int lane = threadIdx.x & 63;
  int row = blockIdx.x * 4 + wv;
  const float* src;
  float* dst;
  bf16* bdst;
  if (row < M) {
    src = y + (size_t)row * DIMS; dst = y2 + row; bdst = yb + (size_t)row * DIMS;
  } else {
    int r = row - M;
    if (r >= B) return;
    src = x + (size_t)r * DIMS; dst = x2 + r; bdst = xb + (size_t)r * DIMS;
  }
  float s = 0.f;
  #pragma unroll
  for (int q = 0; q < DIMS / 4; q += 64) {
    float4 v = ((const float4*)src)[q + lane];
    s = fmaf(v.x, v.x, s); s = fmaf(v.y, v.y, s);
    s = fmaf(v.z, v.z, s); s = fmaf(v.w, v.w, s);
    if (PRE) {
      bf16x4 bv = {(bf16)v.x, (bf16)v.y, (bf16)v.z, (bf16)v.w};
      *(bf16x4*)(bdst + (size_t)(q + lane) * 4) = bv;
    }
  }
  #pragma unroll
  for (int off = 32; off; off >>= 1) s += __shfl_xor(s, off);
  if (lane == 0) *dst = s;
}

// ---------------- phase A: 256x256 bf16 MFMA, 8-phase counted-vmcnt --------
// grid 256 blocks (rowblk = bid>>5, colchunk = bid&31); 512 thr = 8 waves 2Mx4N.
// Per wave 128x64. Per K-tile: 4 phases = 4 C-quadrants x 16 MFMA; raw
// barriers; stage(t+1) at P0/P1; one vmcnt(0) at P3 (>=2 phases after issue).
template<bool PRE>
__global__ __launch_bounds__(512, 2) void knn_mfma8p(
    const float* __restrict__ xf, const float* __restrict__ yf,
    const bf16* __restrict__ xb, const bf16* __restrict__ yb,
    const float* __restrict__ x2, const float* __restrict__ y2,
    float* __restrict__ topk_out,           // [nch][B][8] squared dists
    const int* __restrict__ xsp, const int* __restrict__ ysp,
    int B, int M, int nch) {
  __shared__ __align__(16) char smem[131072]; // 2 x (A 32KB + B 32KB); epilogue reuse
  float* eps = (float*)smem;                  // [128 rows][64 blk of f32x4], rotated
  float* part = (float*)smem;                 // [2][512][9] partial top-8s

  const int tid = threadIdx.x;
  const int wv = tid >> 6;
  const int l = tid & 63;
  const int wr = wv >> 2, wc = wv & 3;
  const int g4 = l >> 4, l16 = l & 15;
  const int rowblk = blockIdx.x >> 5, colchunk = blockIdx.x & 31;
  const int r0 = rowblk * BM;
  const int c0 = colchunk * BN;
  const int xs = *xsp, ys = *ysp;
  const float FINF = __builtin_inff();

  f32x4 acc[8][4];
  #pragma unroll
  for (int mi = 0; mi < 8; ++mi)
    #pragma unroll
    for (int ni = 0; ni < 4; ++ni)
      acc[mi][ni] = (f32x4){0.f, 0.f, 0.f, 0.f};

  // ---- staging: 4 gload_lds each (A tile rows 0..255 / B tile rows = y cols)
  auto STAGE_A = [&](char* buf, int k0) {
    #pragma unroll
    for (int p = 0; p < 4; ++p) {
      int row = p * 64 + (tid >> 3);
      int sl = (tid & 7) ^ (row & 7);        // pre-swizzled global source
      gload_lds16(xb + (size_t)(r0 + row) * DIMS + k0 + sl * 8,
                  buf + p * 8192 + tid * 16);
    }
  };
  auto STAGE_B = [&](char* buf, int k0) {
    #pragma unroll
    for (int p = 0; p < 4; ++p) {
      int row = p * 64 + (tid >> 3);
      int sl = (tid & 7) ^ (row & 7);
      gload_lds16(yb + (size_t)(c0 + row) * DIMS + k0 + sl * 8,
                  buf + p * 8192 + tid * 16);
    }
  };
  // fp32 fallback staging (single buffer, reg convert)
  auto STAGE_CONV = [&](char* abuf, char* bbuf, int k0) {
    #pragma unroll
    for (int p = 0; p < 4; ++p) {
      int row = p * 64 + (tid >> 3);
      int sl = (tid & 7) ^ (row & 7);
      const float* gx = xf + (size_t)(r0 + row) * DIMS + k0 + sl * 8;
      float4 a0 = *(const float4*)gx, a1 = *(const float4*)(gx + 4);
      *(bf16x8*)(abuf + p * 8192 + tid * 16) =
          (bf16x8){(bf16)a0.x, (bf16)a0.y, (bf16)a0.z, (bf16)a0.w,
                   (bf16)a1.x, (bf16)a1.y, (bf16)a1.z, (bf16)a1.w};
      const float* gy = yf + (size_t)(c0 + row) * DIMS + k0 + sl * 8;
      float4 b0 = *(const float4*)gy, b1 = *(const float4*)(gy + 4);
      *(bf16x8*)(bbuf + p * 8192 + tid * 16) =
          (bf16x8){(bf16)b0.x, (bf16)b0.y, (bf16)b0.z, (bf16)b0.w,
                   (bf16)b1.x, (bf16)b1.y, (bf16)b1.z, (bf16)b1.w};
    }
  };

  auto LDA = [&](bf16x8 (&af)[4][2], const char* xd, int mh) { // 8 ds_read_b128
    #pragma unroll
    for (int mi = 0; mi < 4; ++mi)
      #pragma unroll
      for (int kk = 0; kk < 2; ++kk) {
        int row = wr * 128 + mh * 64 + mi * 16 + l16;
        int phys = (kk * 4 + g4) ^ (row & 7);
        af[mi][kk] = *(const bf16x8*)(xd + row * 128 + phys * 16);
      }
  };
  auto LDB = [&](bf16x8 (&bfr)[2][2], const char* yd, int nh) { // 4 ds_read_b128
    #pragma unroll
    for (int ni = 0; ni < 2; ++ni)
      #pragma unroll
      for (int kk = 0; kk < 2; ++kk) {
        int col = wc * 64 + nh * 32 + ni * 16 + l16;
        int phys = (kk * 4 + g4) ^ (col & 7);
        bfr[ni][kk] = *(const bf16x8*)(yd + col * 128 + phys * 16);
      }
  };

#define MFMAQ(AF, BF, MB, NB)                                               \
  {                                                                         \
    __builtin_amdgcn_s_setprio(1);                                          \
    _Pragma("unroll") for (int mi = 0; mi < 4; ++mi)                        \
      _Pragma("unroll") for (int ni = 0; ni < 2; ++ni)                      \
        _Pragma("unroll") for (int kk = 0; kk < 2; ++kk)                    \
          acc[(MB) + mi][(NB) + ni] = __builtin_amdgcn_mfma_f32_16x16x32_bf16( \
              AF[mi][kk], BF[ni][kk], acc[(MB) + mi][(NB) + ni], 0, 0, 0);  \
    __builtin_amdgcn_s_setprio(0);                                          \
  }

  bf16x8 a0f[4][2], a1f[4][2], b0f[2][2], b1f[2][2];

  if (PRE) {
    // prologue: tile 0 into buf0, full drain once
    STAGE_A(smem, 0);
    STAGE_B(smem + 32768, 0);
    __syncthreads();

    #pragma unroll 1
    for (int t = 0; t < NT; ++t) {
      const int cur = t & 1;
      const char* xd = smem + cur * 65536;
      const char* yd = xd + 32768;
      char* nx = smem + (cur ^ 1) * 65536;
      const bool more = (t + 1 < NT);

      // P0: Q(0,0) — 12 ds_read + stage A(t+1)
      LDA(a0f, xd, 0); LDB(b0f, yd, 0);
      if (more) STAGE_A(nx, (t + 1) * KT);
      BAR();
      MFMAQ(a0f, b0f, 0, 0);
      BAR();
      // P1: Q(1,0) — 8 ds_read + stage B(t+1)
      LDA(a1f, xd, 1);
      if (more) STAGE_B(nx + 32768, (t + 1) * KT);
      BAR();
      MFMAQ(a1f, b0f, 4, 0);
      BAR();
      // P2: Q(1,1) — 4 ds_read
      LDB(b1f, yd, 1);
      BAR();
      MFMAQ(a1f, b1f, 4, 2);
      BAR();
      // P3: Q(0,1) — counted wait: loads issued >=2 phases ago
      if (more) asm volatile("s_waitcnt vmcnt(0)" ::: "memory");
      BAR();
      MFMAQ(a0f, b1f, 0, 2);
      BAR();
    }
  } else {
    #pragma unroll 1
    for (int t = 0; t < NT; ++t) {
      __syncthreads();
      STAGE_CONV(smem, smem + 32768, t * KT);
      __syncthreads();
      const char* xd = smem;
      const char* yd = smem + 32768;
      LDA(a0f, xd, 0); LDB(b0f, yd, 0);
      MFMAQ(a0f, b0f, 0, 0);
      LDA(a1f, xd, 1);
      MFMAQ(a1f, b0f, 4, 0);
      LDB(b1f, yd, 1);
      MFMAQ(a1f, b1f, 4, 2);
      MFMAQ(a0f, b1f, 0, 2);
      __syncthreads();
    }
  }

  // ---- epilogue: two 128-row halves through eps (full 128KB), rotated banks
  float t8[2][8];
  #pragma unroll
  for (int h = 0; h < 2; ++h) {
    __syncthreads();
    if (wr == h) {                           // 4 waves write 128x256 f32
      #pragma unroll
      for (int mi = 0; mi < 8; ++mi)
        #pragma unroll
        for (int j = 0; j < 4; ++j) {
          int row = mi * 16 + g4 * 4 + j;    // 0..127 within half
          int gr = r0 + h * 128 + row;
          float xv = x2[gr];
          #pragma unroll
          for (int ni = 0; ni < 4; ++ni) {
            int col = wc * 64 + ni * 16 + l16;
            float sq = fmaxf(xv + y2[c0 + col] - 2.f * acc[mi][ni][j], 0.f);
            if (xs + gr == ys + c0 + col) sq = FINF;
            int phys = ((col >> 2) + row) & 63;   // additive rotation: 2-way free
            eps[row * 256 + phys * 4 + (col & 3)] = sq;
          }
        }
    }
    __syncthreads();
    {
      int row = tid >> 2, q = tid & 3;       // 4 threads/row, 64 cols each
      #pragma unroll
      for (int k = 0; k < 8; ++k) t8[h][k] = FINF;
      #pragma unroll 4
      for (int i = 0; i < 16; ++i) {
        int phys = (q * 16 + i + row) & 63;
        f32x4 v = *(const f32x4*)&eps[row * 256 + phys * 4];
        if (v[0] < t8[h][7]) ins8(t8[h], v[0]);
        if (v[1] < t8[h][7]) ins8(t8[h], v[1]);
        if (v[2] < t8[h][7]) ins8(t8[h], v[2]);
        if (v[3] < t8[h][7]) ins8(t8[h], v[3]);
      }
    }
  }
  __syncthreads();                           // eps dead; reuse as part[2][512][9]
  #pragma unroll
  for (int h = 0; h < 2; ++h)
    #pragma unroll
    for (int k = 0; k < 8; ++k)
      part[(h * 512 + tid) * 9 + k] = t8[h][k];
  __syncthreads();
  if (tid < 256) {                           // merge 4 quarter-scans per row
    int h = tid >> 7, rl = tid & 127;
    float f8[8];
    #pragma unroll
    for (int k = 0; k < 8; ++k) f8[k] = FINF;
    #pragma unroll
    for (int q = 0; q < 4; ++q)
      #pragma unroll
      for (int v = 0; v < 8; ++v) {
        float d = part[(h * 512 + rl * 4 + q) * 9 + v];
        if (d < f8[7]) ins8(f8, d);
      }
    float* o = topk_out + ((size_t)colchunk * B + (r0 + tid)) * 8;
    #pragma unroll
    for (int k = 0; k < 8; ++k) o[k] = f8[k];
  }
}

// ---------------- phase B: merge chunk candidates + running min_dists ------
__global__ void knn_phaseB(const float* __restrict__ topk,
                           const float* __restrict__ mind_in,
                           float* __restrict__ out,
                           const int* __restrict__ xsp, int B, int nch) {
  int r = blockIdx.x * blockDim.x + threadIdx.x;
  if (r >= B) return;
  int x_start = *xsp;
  const float FINF = __builtin_inff();
  float lst[8];
  #pragma unroll
  for (int k = 0; k < 8; ++k) lst[k] = FINF;
  for (int c = 0; c < nch; ++c) {
    const float* bp = topk + ((size_t)c * B + r) * 8;
    #pragma unroll
    for (int k = 0; k < 8; ++k) {
      float d = sqrtf(bp[k]);                // squared -> distance
      if (d < lst[7]) ins8(lst, d);
    }
  }
  const float* cur = mind_in + (size_t)(x_start + r) * KNN_K;
  #pragma unroll
  for (int k = 0; k < 8; ++k) {
    float d = cur[k];
    if (d < lst[7]) ins8(lst, d);
  }
  #pragma unroll
  for (int k = 0; k < 8; ++k) out[(size_t)(x_start + r) * KNN_K + k] = lst[k];
}

extern "C" void kernel_launch(void* const* d_in, const int* in_sizes, int n_in,
                              void* d_out, int out_size, void* d_ws, size_t ws_size,
                              hipStream_t stream) {
  const float* x = (const float*)d_in[0];
  const float* y = (const float*)d_in[1];
  const float* mind = (const float*)d_in[2];
  const int* xsp = (const int*)d_in[3];
  const int* ysp = (const int*)d_in[4];
  float* out = (float*)d_out;

  const int B = in_sizes[0] / DIMS;       // 2048
  const int M = in_sizes[1] / DIMS;       // 8192
  const int nch = M / BN;                 // 32

  float* y2 = (float*)d_ws;               // [M]
  float* x2 = y2 + M;                     // [B]
  float* topk = x2 + B;                   // [nch][B][8]
  size_t base = ((size_t)(M + B) + (size_t)B * nch * 8) * 4;
  base = (base + 255) & ~(size_t)255;
  bf16* xbw = (bf16*)((char*)d_ws + base);
  bf16* ybw = xbw + (size_t)B * DIMS;
  size_t need = base + ((size_t)B + (size_t)M) * DIMS * 2;
  bool pre = ws_size >= need;

  int nNorm = (B + M + 3) / 4;
  int n4 = out_size / 4;
  int nCopy = (n4 + 255) / 256;
  if (pre)
    prep_kernel<true><<<nNorm + nCopy, 256, 0, stream>>>(
        x, y, x2, y2, xbw, ybw, (const float4*)mind, (float4*)out, n4, B, M, nNorm);
  else
    prep_kernel<false><<<nNorm + nCopy, 256, 0, stream>>>(
        x, y, x2, y2, xbw, ybw, (const float4*)mind, (float4*)out, n4, B, M, nNorm);

  int nBlocks = (B / BM) * nch;           // 8 x 32 = 256 (1 block/CU)
  if (pre)
    knn_mfma8p<true><<<nBlocks, 512, 0, stream>>>(x, y, xbw, ybw, x2, y2, topk, xsp, ysp, B, M, nch);
  else
    knn_mfma8p<false><<<nBlocks, 512, 0, stream>>>(x, y, xbw, ybw, x2, y2, topk, xsp, ysp, B, M, nch);

  knn_phaseB<<<(B + 255) / 256, 256, 0, stream>>>(topk, mind, out, xsp, B, nch);
}